// Round 1
// baseline (307.446 us; speedup 1.0000x reference)
//
#include <hip/hip_runtime.h>

// Fusion_loss: 3 modalities of Mahalanobis-distance softmax fusion.
// K=64 classes, Q=128 queries/class, DIM=1024. Rows M = 8192.
// logits_m[r][c] = -(||x_r||^2 - 2 x_r.p_c + ||p_c||^2) / var_c
// loss = mean_r sum_m w_m * (lse_m(r) - logits_m[r][y_r]),  y_r = r/128
// acc  = mean_r [argmax_c sum_m w_m softmax(logits_m)[r][c] == y_r]
//
// Design: f16 MFMA 16x16x32 for the xp cross term (error ~0.02 on logit
// scale ~2000; threshold 40), fp32 for x2/p2/softmax. No LDS: MFMA
// fragments loaded straight from global in native layout (128B segments),
// protos are L2-resident. One wave = 16 rows x all 64 protos.

typedef _Float16 half8 __attribute__((ext_vector_type(8)));
typedef float    floatx4 __attribute__((ext_vector_type(4)));

#define NCLS  64
#define QPC   128
#define DIM   1024
#define NROWS (NCLS * QPC)   // 8192
#define TF_W  1.0f
#define DE_W  0.8f
#define FFT_W 0.6f

__global__ __launch_bounds__(128) void fusion_loss_kernel(
    const float* __restrict__ Xtf, const float* __restrict__ Ptf, const float* __restrict__ Vtf,
    const float* __restrict__ Xde, const float* __restrict__ Pde, const float* __restrict__ Vde,
    const float* __restrict__ Xff, const float* __restrict__ Pff, const float* __restrict__ Vff,
    float* __restrict__ out)
{
    const int tid  = threadIdx.x;
    const int wave = tid >> 6;          // 2 waves per block
    const int lane = tid & 63;
    const int l15  = lane & 15;
    const int quad = lane >> 4;         // 0..3
    const int rowBase = blockIdx.x * 32 + wave * 16;  // 16 rows per wave
    const int myRow   = rowBase + l15;                // row this lane stages A for

    const float* Xs[3] = {Xtf, Xde, Xff};
    const float* Ps[3] = {Ptf, Pde, Pff};
    const float* Vs[3] = {Vtf, Vde, Vff};
    const float  Ws[3] = {TF_W, DE_W, FFT_W};

    // pred_mah accumulator across modalities: pred[t][r] is
    // row = rowBase + quad*4 + r, col = t*16 + l15  (MFMA C/D layout)
    float pred[4][4];
    #pragma unroll
    for (int t = 0; t < 4; ++t)
        #pragma unroll
        for (int r = 0; r < 4; ++r) pred[t][r] = 0.0f;

    float lossAcc = 0.0f;
    float cntAcc  = 0.0f;

    #pragma unroll 1
    for (int m = 0; m < 3; ++m) {
        const float* __restrict__ X = Xs[m];
        const float* __restrict__ P = Ps[m];
        const float* __restrict__ V = Vs[m];
        const float  w = Ws[m];

        floatx4 d[4];
        #pragma unroll
        for (int t = 0; t < 4; ++t) d[t] = (floatx4){0.f, 0.f, 0.f, 0.f};
        float x2p    = 0.0f;           // partial ||x_row||^2 for row l15 (k-slice of this quad)
        float p2p[4] = {0.f, 0.f, 0.f, 0.f};  // partial ||p_col||^2, col = t*16+l15

        // A fragment source: lane l reads X[myRow][kc*32 + quad*8 .. +8]
        const float* xrow = X + (size_t)myRow * DIM + quad * 8;
        const float* prow[4];
        #pragma unroll
        for (int t = 0; t < 4; ++t)
            prow[t] = P + (size_t)(t * 16 + l15) * DIM + quad * 8;

        #pragma unroll 2
        for (int kc = 0; kc < DIM / 32; ++kc) {
            const int ko = kc * 32;
            const float4 a0 = *reinterpret_cast<const float4*>(xrow + ko);
            const float4 a1 = *reinterpret_cast<const float4*>(xrow + ko + 4);
            float4 b0[4], b1[4];
            #pragma unroll
            for (int t = 0; t < 4; ++t) {
                b0[t] = *reinterpret_cast<const float4*>(prow[t] + ko);
                b1[t] = *reinterpret_cast<const float4*>(prow[t] + ko + 4);
            }

            x2p += a0.x*a0.x + a0.y*a0.y + a0.z*a0.z + a0.w*a0.w
                 + a1.x*a1.x + a1.y*a1.y + a1.z*a1.z + a1.w*a1.w;

            half8 af;
            af[0] = (_Float16)a0.x; af[1] = (_Float16)a0.y;
            af[2] = (_Float16)a0.z; af[3] = (_Float16)a0.w;
            af[4] = (_Float16)a1.x; af[5] = (_Float16)a1.y;
            af[6] = (_Float16)a1.z; af[7] = (_Float16)a1.w;

            #pragma unroll
            for (int t = 0; t < 4; ++t) {
                p2p[t] += b0[t].x*b0[t].x + b0[t].y*b0[t].y + b0[t].z*b0[t].z + b0[t].w*b0[t].w
                        + b1[t].x*b1[t].x + b1[t].y*b1[t].y + b1[t].z*b1[t].z + b1[t].w*b1[t].w;
                half8 bf;
                bf[0] = (_Float16)b0[t].x; bf[1] = (_Float16)b0[t].y;
                bf[2] = (_Float16)b0[t].z; bf[3] = (_Float16)b0[t].w;
                bf[4] = (_Float16)b1[t].x; bf[5] = (_Float16)b1[t].y;
                bf[6] = (_Float16)b1[t].z; bf[7] = (_Float16)b1[t].w;
                d[t] = __builtin_amdgcn_mfma_f32_16x16x32_f16(af, bf, d[t], 0, 0, 0);
            }
        }

        // complete x2 (row l15) and p2 (col t*16+l15) across the 4 quads
        x2p += __shfl_xor(x2p, 16);
        x2p += __shfl_xor(x2p, 32);
        #pragma unroll
        for (int t = 0; t < 4; ++t) {
            p2p[t] += __shfl_xor(p2p[t], 16);
            p2p[t] += __shfl_xor(p2p[t], 32);
        }
        // redistribute x2 to C/D row indexing: need x2 of row quad*4+r
        float x2r[4];
        #pragma unroll
        for (int r = 0; r < 4; ++r) x2r[r] = __shfl(x2p, quad * 4 + r);

        float vc[4];
        #pragma unroll
        for (int t = 0; t < 4; ++t) vc[t] = V[t * 16 + l15];

        #pragma unroll
        for (int r = 0; r < 4; ++r) {
            float lg[4];
            #pragma unroll
            for (int t = 0; t < 4; ++t)
                lg[t] = (2.0f * d[t][r] - x2r[r] - p2p[t]) / vc[t];

            // row softmax over 64 cols: 4 in-lane + 16-lane butterfly
            float mx = fmaxf(fmaxf(lg[0], lg[1]), fmaxf(lg[2], lg[3]));
            #pragma unroll
            for (int dl = 1; dl <= 8; dl <<= 1) mx = fmaxf(mx, __shfl_xor(mx, dl));
            float s = expf(lg[0] - mx) + expf(lg[1] - mx)
                    + expf(lg[2] - mx) + expf(lg[3] - mx);
            #pragma unroll
            for (int dl = 1; dl <= 8; dl <<= 1) s += __shfl_xor(s, dl);
            const float lse = mx + logf(s);

            const int R = rowBase + quad * 4 + r;
            const int y = R >> 7;   // /QPC
            #pragma unroll
            for (int t = 0; t < 4; ++t) {
                const int col = t * 16 + l15;
                if (col == y) lossAcc += w * (lse - lg[t]);   // -w*log_softmax at target
                pred[t][r] += w * expf(lg[t] - lse);          // w*softmax
            }
        }
    }

    // argmax over fused pred per row (first-max tie-break = lowest col)
    #pragma unroll
    for (int r = 0; r < 4; ++r) {
        float bv = -1.0f; int bc = 0;
        #pragma unroll
        for (int t = 0; t < 4; ++t) {
            const float v = pred[t][r];
            const int   c = t * 16 + l15;
            if (v > bv) { bv = v; bc = c; }   // ascending c in-lane: keeps lowest on tie
        }
        #pragma unroll
        for (int dl = 1; dl <= 8; dl <<= 1) {
            const float ov = __shfl_xor(bv, dl);
            const int   oc = __shfl_xor(bc, dl);
            if (ov > bv || (ov == bv && oc < bc)) { bv = ov; bc = oc; }
        }
        const int R = rowBase + quad * 4 + r;
        const int y = R >> 7;
        if (l15 == 0 && bc == y) cntAcc += 1.0f;
    }

    // wave reduce, then block reduce, then global atomics
    #pragma unroll
    for (int dl = 1; dl <= 32; dl <<= 1) {
        lossAcc += __shfl_xor(lossAcc, dl);
        cntAcc  += __shfl_xor(cntAcc, dl);
    }
    __shared__ float sl[2], sc[2];
    if (lane == 0) { sl[wave] = lossAcc; sc[wave] = cntAcc; }
    __syncthreads();
    if (tid == 0) {
        atomicAdd(&out[0], (sl[0] + sl[1]) * (1.0f / NROWS));
        atomicAdd(&out[1], (sc[0] + sc[1]) * (1.0f / NROWS));
    }
}

extern "C" void kernel_launch(void* const* d_in, const int* in_sizes, int n_in,
                              void* d_out, int out_size, void* d_ws, size_t ws_size,
                              hipStream_t stream) {
    const float* Xtf = (const float*)d_in[0];
    const float* Ptf = (const float*)d_in[1];
    const float* Vtf = (const float*)d_in[2];
    const float* Xde = (const float*)d_in[3];
    const float* Pde = (const float*)d_in[4];
    const float* Vde = (const float*)d_in[5];
    const float* Xff = (const float*)d_in[6];
    const float* Pff = (const float*)d_in[7];
    const float* Vff = (const float*)d_in[8];
    float* out = (float*)d_out;

    // d_out is poisoned 0xAA before every timed replay -> zero it on-stream
    hipMemsetAsync(out, 0, 2 * sizeof(float), stream);

    // 8192 rows / 32 rows-per-block = 256 blocks, 128 threads (2 waves)
    fusion_loss_kernel<<<dim3(NROWS / 32), dim3(128), 0, stream>>>(
        Xtf, Ptf, Vtf, Xde, Pde, Vde, Xff, Pff, Vff, out);
}

// Round 2
// 196.437 us; speedup vs baseline: 1.5651x; 1.5651x over previous
//
#include <hip/hip_runtime.h>

// Fusion_loss: 3 modalities of Mahalanobis-distance softmax fusion.
// K=64 classes, Q=128 queries/class, DIM=1024. Rows M = 8192.
// logits_m[r][c] = -(||x_r||^2 - 2 x_r.p_c + ||p_c||^2) / var_c
// loss = mean_r sum_m w_m * (lse_m(r) - logits_m[r][y_r]),  y_r = r/128
// acc  = mean_r [argmax_c sum_m w_m softmax(logits_m)[r][c] == y_r]
//
// R2: latency-bound fix. R1 had 2 waves/CU, 68 VGPRs -> loads fully
// serialized (960 loads x ~500cyc ~= 205us, matched measurement).
// Now: block = 12 waves (3 modalities x 4 K-slices) x 16 rows,
// grid = 512 blocks -> up to 24 waves/CU. Partials reduced via LDS.

typedef _Float16 half8 __attribute__((ext_vector_type(8)));
typedef float    floatx4 __attribute__((ext_vector_type(4)));

#define NCLS   64
#define QPC    128
#define DIM    1024
#define NROWS  (NCLS * QPC)      // 8192
#define KSPLIT 4
#define KSLICE (DIM / KSPLIT)    // 256
#define NITER  (KSLICE / 32)     // 8 MFMA k-chunks per wave
#define NWAVES 12                // 3 modalities x 4 k-slices
#define DSTRIDE 17               // padded per-lane stride (floats) for dpart
#define PSTRIDE 65               // padded row stride for pred tile

__global__ __launch_bounds__(NWAVES * 64) void fusion_loss_kernel(
    const float* __restrict__ Xtf, const float* __restrict__ Ptf, const float* __restrict__ Vtf,
    const float* __restrict__ Xde, const float* __restrict__ Pde, const float* __restrict__ Vde,
    const float* __restrict__ Xff, const float* __restrict__ Pff, const float* __restrict__ Vff,
    float* __restrict__ out)
{
    // partial MFMA tiles: per wave, per lane 16 floats (idx = t*4 + r), padded
    __shared__ float dpart[NWAVES][64 * DSTRIDE];     // 52224 B
    __shared__ float x2part[NWAVES][16];              //   768 B
    __shared__ float p2part[NWAVES][64];              //  3072 B
    __shared__ float predL[16 * PSTRIDE];             //  4160 B
    __shared__ float lossL;

    const int tid  = threadIdx.x;
    const int wave = tid >> 6;        // 0..11
    const int lane = tid & 63;
    const int l15  = lane & 15;
    const int quad = lane >> 4;       // 0..3
    const int m    = wave >> 2;       // modality 0..2
    const int kq   = wave & 3;        // k-slice 0..3
    const int rowBase = blockIdx.x * 16;

    // zero the fused-pred tile + loss scalar (first barrier orders vs use)
    for (int i = tid; i < 16 * PSTRIDE; i += NWAVES * 64) predL[i] = 0.0f;
    if (tid == 0) lossL = 0.0f;

    const float* __restrict__ X = (m == 0) ? Xtf : (m == 1) ? Xde : Xff;
    const float* __restrict__ P = (m == 0) ? Ptf : (m == 1) ? Pde : Pff;
    const float* __restrict__ V = (m == 0) ? Vtf : (m == 1) ? Vde : Vff;
    const float  w = (m == 0) ? 1.0f : (m == 1) ? 0.8f : 0.6f;

    floatx4 d[4];
    #pragma unroll
    for (int t = 0; t < 4; ++t) d[t] = (floatx4){0.f, 0.f, 0.f, 0.f};
    float x2p    = 0.0f;                   // partial ||x_row||^2, row l15, this k-slice
    float p2p[4] = {0.f, 0.f, 0.f, 0.f};   // partial ||p_col||^2, col t*16+l15

    // A fragment: lane reads X[rowBase+l15][kq*256 + kc*32 + quad*8 .. +8]
    const float* xrow = X + (size_t)(rowBase + l15) * DIM + kq * KSLICE + quad * 8;
    const float* prow[4];
    #pragma unroll
    for (int t = 0; t < 4; ++t)
        prow[t] = P + (size_t)(t * 16 + l15) * DIM + kq * KSLICE + quad * 8;

    #pragma unroll 2
    for (int kc = 0; kc < NITER; ++kc) {
        const int ko = kc * 32;
        const float4 a0 = *reinterpret_cast<const float4*>(xrow + ko);
        const float4 a1 = *reinterpret_cast<const float4*>(xrow + ko + 4);
        float4 b0[4], b1[4];
        #pragma unroll
        for (int t = 0; t < 4; ++t) {
            b0[t] = *reinterpret_cast<const float4*>(prow[t] + ko);
            b1[t] = *reinterpret_cast<const float4*>(prow[t] + ko + 4);
        }

        x2p += a0.x*a0.x + a0.y*a0.y + a0.z*a0.z + a0.w*a0.w
             + a1.x*a1.x + a1.y*a1.y + a1.z*a1.z + a1.w*a1.w;

        half8 af;
        af[0] = (_Float16)a0.x; af[1] = (_Float16)a0.y;
        af[2] = (_Float16)a0.z; af[3] = (_Float16)a0.w;
        af[4] = (_Float16)a1.x; af[5] = (_Float16)a1.y;
        af[6] = (_Float16)a1.z; af[7] = (_Float16)a1.w;

        #pragma unroll
        for (int t = 0; t < 4; ++t) {
            p2p[t] += b0[t].x*b0[t].x + b0[t].y*b0[t].y + b0[t].z*b0[t].z + b0[t].w*b0[t].w
                    + b1[t].x*b1[t].x + b1[t].y*b1[t].y + b1[t].z*b1[t].z + b1[t].w*b1[t].w;
            half8 bf;
            bf[0] = (_Float16)b0[t].x; bf[1] = (_Float16)b0[t].y;
            bf[2] = (_Float16)b0[t].z; bf[3] = (_Float16)b0[t].w;
            bf[4] = (_Float16)b1[t].x; bf[5] = (_Float16)b1[t].y;
            bf[6] = (_Float16)b1[t].z; bf[7] = (_Float16)b1[t].w;
            d[t] = __builtin_amdgcn_mfma_f32_16x16x32_f16(af, bf, d[t], 0, 0, 0);
        }
    }

    // complete this k-slice's x2/p2 across the 4 quads
    x2p += __shfl_xor(x2p, 16);
    x2p += __shfl_xor(x2p, 32);
    #pragma unroll
    for (int t = 0; t < 4; ++t) {
        p2p[t] += __shfl_xor(p2p[t], 16);
        p2p[t] += __shfl_xor(p2p[t], 32);
    }

    // stash partials in LDS
    {
        float* dp = &dpart[wave][lane * DSTRIDE];
        #pragma unroll
        for (int t = 0; t < 4; ++t)
            *reinterpret_cast<float4*>(dp + t * 4) =
                make_float4(d[t][0], d[t][1], d[t][2], d[t][3]);
        if (quad == 0) {
            x2part[wave][l15] = x2p;
            #pragma unroll
            for (int t = 0; t < 4; ++t) p2part[wave][t * 16 + l15] = p2p[t];
        }
    }
    __syncthreads();

    const int y = rowBase >> 7;   // class uniform across the block's 16 rows

    if (kq == 0) {
        // epilogue wave for modality m: reduce the 4 k-slice partials
        floatx4 dsum[4];
        #pragma unroll
        for (int t = 0; t < 4; ++t) dsum[t] = (floatx4){0.f, 0.f, 0.f, 0.f};
        float x2r[4] = {0.f, 0.f, 0.f, 0.f};
        float p2c[4] = {0.f, 0.f, 0.f, 0.f};
        #pragma unroll
        for (int k2 = 0; k2 < KSPLIT; ++k2) {
            const int wv = m * 4 + k2;
            const float* src = &dpart[wv][lane * DSTRIDE];
            #pragma unroll
            for (int t = 0; t < 4; ++t) {
                const float4 v = *reinterpret_cast<const float4*>(src + t * 4);
                dsum[t][0] += v.x; dsum[t][1] += v.y; dsum[t][2] += v.z; dsum[t][3] += v.w;
            }
            #pragma unroll
            for (int r = 0; r < 4; ++r) x2r[r] += x2part[wv][quad * 4 + r];
            #pragma unroll
            for (int t = 0; t < 4; ++t) p2c[t] += p2part[wv][t * 16 + l15];
        }
        float vc[4];
        #pragma unroll
        for (int t = 0; t < 4; ++t) vc[t] = V[t * 16 + l15];

        float lossAcc = 0.0f;
        #pragma unroll
        for (int r = 0; r < 4; ++r) {
            float lg[4];
            #pragma unroll
            for (int t = 0; t < 4; ++t)
                lg[t] = (2.0f * dsum[t][r] - x2r[r] - p2c[t]) / vc[t];

            float mx = fmaxf(fmaxf(lg[0], lg[1]), fmaxf(lg[2], lg[3]));
            #pragma unroll
            for (int dl = 1; dl <= 8; dl <<= 1) mx = fmaxf(mx, __shfl_xor(mx, dl));
            float s = expf(lg[0] - mx) + expf(lg[1] - mx)
                    + expf(lg[2] - mx) + expf(lg[3] - mx);
            #pragma unroll
            for (int dl = 1; dl <= 8; dl <<= 1) s += __shfl_xor(s, dl);
            const float lse = mx + logf(s);

            const int row = quad * 4 + r;
            #pragma unroll
            for (int t = 0; t < 4; ++t) {
                const int col = t * 16 + l15;
                if (col == y) lossAcc += w * (lse - lg[t]);
                atomicAdd(&predL[row * PSTRIDE + col], w * expf(lg[t] - lse));
            }
        }
        #pragma unroll
        for (int dl = 1; dl <= 32; dl <<= 1) lossAcc += __shfl_xor(lossAcc, dl);
        if (lane == 0) atomicAdd(&lossL, lossAcc);
    }
    __syncthreads();

    if (wave == 0) {
        // fused argmax per row; first-max tie-break = lowest col
        float cnt = 0.0f;
        #pragma unroll 1
        for (int r = 0; r < 16; ++r) {
            float bv = predL[r * PSTRIDE + lane];
            int   bc = lane;
            #pragma unroll
            for (int dl = 1; dl <= 32; dl <<= 1) {
                const float ov = __shfl_xor(bv, dl);
                const int   oc = __shfl_xor(bc, dl);
                if (ov > bv || (ov == bv && oc < bc)) { bv = ov; bc = oc; }
            }
            if (lane == 0 && bc == y) cnt += 1.0f;
        }
        if (lane == 0) {
            atomicAdd(&out[0], lossL * (1.0f / NROWS));
            atomicAdd(&out[1], cnt * (1.0f / NROWS));
        }
    }
}

extern "C" void kernel_launch(void* const* d_in, const int* in_sizes, int n_in,
                              void* d_out, int out_size, void* d_ws, size_t ws_size,
                              hipStream_t stream) {
    const float* Xtf = (const float*)d_in[0];
    const float* Ptf = (const float*)d_in[1];
    const float* Vtf = (const float*)d_in[2];
    const float* Xde = (const float*)d_in[3];
    const float* Pde = (const float*)d_in[4];
    const float* Vde = (const float*)d_in[5];
    const float* Xff = (const float*)d_in[6];
    const float* Pff = (const float*)d_in[7];
    const float* Vff = (const float*)d_in[8];
    float* out = (float*)d_out;

    // d_out is poisoned 0xAA before every timed replay -> zero it on-stream
    hipMemsetAsync(out, 0, 2 * sizeof(float), stream);

    // 8192 rows / 16 rows-per-block = 512 blocks, 768 threads (12 waves)
    fusion_loss_kernel<<<dim3(NROWS / 16), dim3(NWAVES * 64), 0, stream>>>(
        Xtf, Ptf, Vtf, Xde, Pde, Vde, Xff, Pff, Vff, out);
}

// Round 3
// 170.339 us; speedup vs baseline: 1.8049x; 1.1532x over previous
//
#include <hip/hip_runtime.h>

// Fusion_loss: 3 modalities of Mahalanobis-distance softmax fusion.
// K=64 classes, Q=128 queries/class, DIM=1024. Rows M = 8192.
// logits_m[r][c] = -(||x_r||^2 - 2 x_r.p_c + ||p_c||^2) / var_c
// loss = mean_r sum_m w_m * (lse_m(r) - logits_m[r][y_r]),  y_r = r/128
// acc  = mean_r [argmax_c sum_m w_m softmax(logits_m)[r][c] == y_r]
//
// R3: segment-rate fix. R2's loads were 16-way segmented (lane l15 -> rows
// 4KB apart): ~31k segments/CU ~= the measured 93us. Now protos are
// pre-converted to f16 in MFMA B-frag layout by a prep kernel (main-kernel
// B load = one coalesced dwordx4), p2 precomputed. Only the one-pass A
// stream stays segmented. launch_bounds(768,3) lifts VGPR cap for MLP.

typedef _Float16 half8 __attribute__((ext_vector_type(8)));
typedef float    floatx4 __attribute__((ext_vector_type(4)));

#define NCLS   64
#define QPC    128
#define DIM    1024
#define NROWS  (NCLS * QPC)      // 8192
#define KSPLIT 4
#define KSLICE (DIM / KSPLIT)    // 256
#define NITER  (KSLICE / 32)     // 8 MFMA k-chunks per wave
#define NWAVES 12                // 3 modalities x 4 k-slices
#define DSTRIDE 17               // padded per-lane stride (floats) for dpart
#define PSTRIDE 65               // padded row stride for pred tile

// ws layout: [0, 393216) f16 protos in B-frag layout; [393216, +768) p2
#define WPROTO_BYTES (3 * NCLS * DIM * 2)          // 393216
#define WS_NEED      (WPROTO_BYTES + 3 * NCLS * 4) // + p2

// ---------------- prep: protos -> f16 B-frag layout + p2 ----------------
// grid 96 blocks (m in 0..2, kcg in 0..31), 64 threads.
// Unit (m,kcg,t) = 1KB: lane l holds 8 halves = B-frag of col t*16+(l&15),
// k = kcg*32 + (l>>4)*8 .. +8.  p2[m*64+c] accumulated via atomics.
__global__ __launch_bounds__(64) void prep_protos(
    const float* __restrict__ Ptf, const float* __restrict__ Pde,
    const float* __restrict__ Pff, _Float16* __restrict__ W,
    float* __restrict__ p2)
{
    const int m    = blockIdx.x >> 5;
    const int kcg  = blockIdx.x & 31;
    const int lane = threadIdx.x;
    const int l15  = lane & 15;
    const int quad = lane >> 4;
    const float* __restrict__ P = (m == 0) ? Ptf : (m == 1) ? Pde : Pff;

    #pragma unroll
    for (int t = 0; t < 4; ++t) {
        const float* src = P + (size_t)(t * 16 + l15) * DIM + kcg * 32 + quad * 8;
        const float4 b0 = *reinterpret_cast<const float4*>(src);
        const float4 b1 = *reinterpret_cast<const float4*>(src + 4);
        half8 h;
        h[0] = (_Float16)b0.x; h[1] = (_Float16)b0.y;
        h[2] = (_Float16)b0.z; h[3] = (_Float16)b0.w;
        h[4] = (_Float16)b1.x; h[5] = (_Float16)b1.y;
        h[6] = (_Float16)b1.z; h[7] = (_Float16)b1.w;
        *reinterpret_cast<half8*>(W + ((size_t)(m * 32 + kcg) * 4 + t) * 512 + lane * 8) = h;

        float s = b0.x*b0.x + b0.y*b0.y + b0.z*b0.z + b0.w*b0.w
                + b1.x*b1.x + b1.y*b1.y + b1.z*b1.z + b1.w*b1.w;
        s += __shfl_xor(s, 16);
        s += __shfl_xor(s, 32);
        if (quad == 0) atomicAdd(&p2[m * 64 + t * 16 + l15], s);
    }
}

// ---------------- main kernel ----------------
__global__ __launch_bounds__(NWAVES * 64, 3) void fusion_loss_kernel(
    const float* __restrict__ Xtf, const float* __restrict__ Vtf,
    const float* __restrict__ Xde, const float* __restrict__ Vde,
    const float* __restrict__ Xff, const float* __restrict__ Vff,
    const _Float16* __restrict__ W, const float* __restrict__ p2g,
    float* __restrict__ out)
{
    __shared__ float dpart[NWAVES][64 * DSTRIDE];     // 52224 B
    __shared__ float x2part[NWAVES][16];              //   768 B
    __shared__ float predL[16 * PSTRIDE];             //  4160 B
    __shared__ float lossL;

    const int tid  = threadIdx.x;
    const int wave = tid >> 6;        // 0..11
    const int lane = tid & 63;
    const int l15  = lane & 15;
    const int quad = lane >> 4;       // 0..3
    const int m    = wave >> 2;       // modality 0..2
    const int kq   = wave & 3;        // k-slice 0..3
    const int rowBase = blockIdx.x * 16;

    for (int i = tid; i < 16 * PSTRIDE; i += NWAVES * 64) predL[i] = 0.0f;
    if (tid == 0) lossL = 0.0f;

    const float* __restrict__ X = (m == 0) ? Xtf : (m == 1) ? Xde : Xff;
    const float* __restrict__ V = (m == 0) ? Vtf : (m == 1) ? Vde : Vff;
    const float  w = (m == 0) ? 1.0f : (m == 1) ? 0.8f : 0.6f;

    floatx4 d[4];
    #pragma unroll
    for (int t = 0; t < 4; ++t) d[t] = (floatx4){0.f, 0.f, 0.f, 0.f};
    float x2p = 0.0f;                  // partial ||x_row||^2, row l15, this k-slice

    // A frag: lane reads X[rowBase+l15][kq*256 + kc*32 + quad*8 .. +8]
    const float* xrow = X + (size_t)(rowBase + l15) * DIM + kq * KSLICE + quad * 8;
    // B frags: coalesced f16 units, 16B/lane
    const _Float16* wbase = W + (size_t)(m * 32 + kq * NITER) * 4 * 512 + lane * 8;

    #pragma unroll 4
    for (int kc = 0; kc < NITER; ++kc) {
        const int ko = kc * 32;
        const float4 a0 = *reinterpret_cast<const float4*>(xrow + ko);
        const float4 a1 = *reinterpret_cast<const float4*>(xrow + ko + 4);
        half8 bf[4];
        #pragma unroll
        for (int t = 0; t < 4; ++t)
            bf[t] = *reinterpret_cast<const half8*>(wbase + (size_t)(kc * 4 + t) * 512);

        x2p += a0.x*a0.x + a0.y*a0.y + a0.z*a0.z + a0.w*a0.w
             + a1.x*a1.x + a1.y*a1.y + a1.z*a1.z + a1.w*a1.w;

        half8 af;
        af[0] = (_Float16)a0.x; af[1] = (_Float16)a0.y;
        af[2] = (_Float16)a0.z; af[3] = (_Float16)a0.w;
        af[4] = (_Float16)a1.x; af[5] = (_Float16)a1.y;
        af[6] = (_Float16)a1.z; af[7] = (_Float16)a1.w;

        #pragma unroll
        for (int t = 0; t < 4; ++t)
            d[t] = __builtin_amdgcn_mfma_f32_16x16x32_f16(af, bf[t], d[t], 0, 0, 0);
    }

    // complete this k-slice's x2 across the 4 quads
    x2p += __shfl_xor(x2p, 16);
    x2p += __shfl_xor(x2p, 32);

    {
        float* dp = &dpart[wave][lane * DSTRIDE];
        #pragma unroll
        for (int t = 0; t < 4; ++t)
            *reinterpret_cast<float4*>(dp + t * 4) =
                make_float4(d[t][0], d[t][1], d[t][2], d[t][3]);
        if (quad == 0) x2part[wave][l15] = x2p;
    }
    __syncthreads();

    const int y = rowBase >> 7;   // class uniform across the block's 16 rows

    if (kq == 0) {
        // epilogue wave for modality m: reduce the 4 k-slice partials
        floatx4 dsum[4];
        #pragma unroll
        for (int t = 0; t < 4; ++t) dsum[t] = (floatx4){0.f, 0.f, 0.f, 0.f};
        float x2r[4] = {0.f, 0.f, 0.f, 0.f};
        #pragma unroll
        for (int k2 = 0; k2 < KSPLIT; ++k2) {
            const int wv = m * 4 + k2;
            const float* src = &dpart[wv][lane * DSTRIDE];
            #pragma unroll
            for (int t = 0; t < 4; ++t) {
                const float4 v = *reinterpret_cast<const float4*>(src + t * 4);
                dsum[t][0] += v.x; dsum[t][1] += v.y; dsum[t][2] += v.z; dsum[t][3] += v.w;
            }
            #pragma unroll
            for (int r = 0; r < 4; ++r) x2r[r] += x2part[wv][quad * 4 + r];
        }
        float vc[4], p2c[4];
        #pragma unroll
        for (int t = 0; t < 4; ++t) {
            vc[t]  = V[t * 16 + l15];
            p2c[t] = p2g[m * 64 + t * 16 + l15];
        }

        float lossAcc = 0.0f;
        #pragma unroll
        for (int r = 0; r < 4; ++r) {
            float lg[4];
            #pragma unroll
            for (int t = 0; t < 4; ++t)
                lg[t] = (2.0f * dsum[t][r] - x2r[r] - p2c[t]) / vc[t];

            float mx = fmaxf(fmaxf(lg[0], lg[1]), fmaxf(lg[2], lg[3]));
            #pragma unroll
            for (int dl = 1; dl <= 8; dl <<= 1) mx = fmaxf(mx, __shfl_xor(mx, dl));
            float s = expf(lg[0] - mx) + expf(lg[1] - mx)
                    + expf(lg[2] - mx) + expf(lg[3] - mx);
            #pragma unroll
            for (int dl = 1; dl <= 8; dl <<= 1) s += __shfl_xor(s, dl);
            const float lse = mx + logf(s);

            const int row = quad * 4 + r;
            #pragma unroll
            for (int t = 0; t < 4; ++t) {
                const int col = t * 16 + l15;
                if (col == y) lossAcc += w * (lse - lg[t]);
                atomicAdd(&predL[row * PSTRIDE + col], w * expf(lg[t] - lse));
            }
        }
        #pragma unroll
        for (int dl = 1; dl <= 32; dl <<= 1) lossAcc += __shfl_xor(lossAcc, dl);
        if (lane == 0) atomicAdd(&lossL, lossAcc);
    }
    __syncthreads();

    if (wave == 0) {
        // fused argmax per row; first-max tie-break = lowest col
        float cnt = 0.0f;
        #pragma unroll 1
        for (int r = 0; r < 16; ++r) {
            float bv = predL[r * PSTRIDE + lane];
            int   bc = lane;
            #pragma unroll
            for (int dl = 1; dl <= 32; dl <<= 1) {
                const float ov = __shfl_xor(bv, dl);
                const int   oc = __shfl_xor(bc, dl);
                if (ov > bv || (ov == bv && oc < bc)) { bv = ov; bc = oc; }
            }
            if (lane == 0 && bc == y) cnt += 1.0f;
        }
        if (lane == 0) {
            atomicAdd(&out[0], lossL * (1.0f / NROWS));
            atomicAdd(&out[1], cnt * (1.0f / NROWS));
        }
    }
}

// ---------------- fallback (R2 kernel, used only if ws too small) --------
__global__ __launch_bounds__(NWAVES * 64) void fusion_loss_fallback(
    const float* __restrict__ Xtf, const float* __restrict__ Ptf, const float* __restrict__ Vtf,
    const float* __restrict__ Xde, const float* __restrict__ Pde, const float* __restrict__ Vde,
    const float* __restrict__ Xff, const float* __restrict__ Pff, const float* __restrict__ Vff,
    float* __restrict__ out)
{
    __shared__ float dpart[NWAVES][64 * DSTRIDE];
    __shared__ float x2part[NWAVES][16];
    __shared__ float p2part[NWAVES][64];
    __shared__ float predL[16 * PSTRIDE];
    __shared__ float lossL;

    const int tid  = threadIdx.x;
    const int wave = tid >> 6;
    const int lane = tid & 63;
    const int l15  = lane & 15;
    const int quad = lane >> 4;
    const int m    = wave >> 2;
    const int kq   = wave & 3;
    const int rowBase = blockIdx.x * 16;

    for (int i = tid; i < 16 * PSTRIDE; i += NWAVES * 64) predL[i] = 0.0f;
    if (tid == 0) lossL = 0.0f;

    const float* __restrict__ X = (m == 0) ? Xtf : (m == 1) ? Xde : Xff;
    const float* __restrict__ P = (m == 0) ? Ptf : (m == 1) ? Pde : Pff;
    const float* __restrict__ V = (m == 0) ? Vtf : (m == 1) ? Vde : Vff;
    const float  w = (m == 0) ? 1.0f : (m == 1) ? 0.8f : 0.6f;

    floatx4 d[4];
    #pragma unroll
    for (int t = 0; t < 4; ++t) d[t] = (floatx4){0.f, 0.f, 0.f, 0.f};
    float x2p    = 0.0f;
    float p2p[4] = {0.f, 0.f, 0.f, 0.f};

    const float* xrow = X + (size_t)(rowBase + l15) * DIM + kq * KSLICE + quad * 8;
    const float* prow[4];
    #pragma unroll
    for (int t = 0; t < 4; ++t)
        prow[t] = P + (size_t)(t * 16 + l15) * DIM + kq * KSLICE + quad * 8;

    #pragma unroll 2
    for (int kc = 0; kc < NITER; ++kc) {
        const int ko = kc * 32;
        const float4 a0 = *reinterpret_cast<const float4*>(xrow + ko);
        const float4 a1 = *reinterpret_cast<const float4*>(xrow + ko + 4);
        float4 b0[4], b1[4];
        #pragma unroll
        for (int t = 0; t < 4; ++t) {
            b0[t] = *reinterpret_cast<const float4*>(prow[t] + ko);
            b1[t] = *reinterpret_cast<const float4*>(prow[t] + ko + 4);
        }
        x2p += a0.x*a0.x + a0.y*a0.y + a0.z*a0.z + a0.w*a0.w
             + a1.x*a1.x + a1.y*a1.y + a1.z*a1.z + a1.w*a1.w;
        half8 af;
        af[0] = (_Float16)a0.x; af[1] = (_Float16)a0.y;
        af[2] = (_Float16)a0.z; af[3] = (_Float16)a0.w;
        af[4] = (_Float16)a1.x; af[5] = (_Float16)a1.y;
        af[6] = (_Float16)a1.z; af[7] = (_Float16)a1.w;
        #pragma unroll
        for (int t = 0; t < 4; ++t) {
            p2p[t] += b0[t].x*b0[t].x + b0[t].y*b0[t].y + b0[t].z*b0[t].z + b0[t].w*b0[t].w
                    + b1[t].x*b1[t].x + b1[t].y*b1[t].y + b1[t].z*b1[t].z + b1[t].w*b1[t].w;
            half8 bf;
            bf[0] = (_Float16)b0[t].x; bf[1] = (_Float16)b0[t].y;
            bf[2] = (_Float16)b0[t].z; bf[3] = (_Float16)b0[t].w;
            bf[4] = (_Float16)b1[t].x; bf[5] = (_Float16)b1[t].y;
            bf[6] = (_Float16)b1[t].z; bf[7] = (_Float16)b1[t].w;
            d[t] = __builtin_amdgcn_mfma_f32_16x16x32_f16(af, bf, d[t], 0, 0, 0);
        }
    }

    x2p += __shfl_xor(x2p, 16);
    x2p += __shfl_xor(x2p, 32);
    #pragma unroll
    for (int t = 0; t < 4; ++t) {
        p2p[t] += __shfl_xor(p2p[t], 16);
        p2p[t] += __shfl_xor(p2p[t], 32);
    }
    {
        float* dp = &dpart[wave][lane * DSTRIDE];
        #pragma unroll
        for (int t = 0; t < 4; ++t)
            *reinterpret_cast<float4*>(dp + t * 4) =
                make_float4(d[t][0], d[t][1], d[t][2], d[t][3]);
        if (quad == 0) {
            x2part[wave][l15] = x2p;
            #pragma unroll
            for (int t = 0; t < 4; ++t) p2part[wave][t * 16 + l15] = p2p[t];
        }
    }
    __syncthreads();

    const int y = rowBase >> 7;

    if (kq == 0) {
        floatx4 dsum[4];
        #pragma unroll
        for (int t = 0; t < 4; ++t) dsum[t] = (floatx4){0.f, 0.f, 0.f, 0.f};
        float x2r[4] = {0.f, 0.f, 0.f, 0.f};
        float p2c[4] = {0.f, 0.f, 0.f, 0.f};
        #pragma unroll
        for (int k2 = 0; k2 < KSPLIT; ++k2) {
            const int wv = m * 4 + k2;
            const float* src = &dpart[wv][lane * DSTRIDE];
            #pragma unroll
            for (int t = 0; t < 4; ++t) {
                const float4 v = *reinterpret_cast<const float4*>(src + t * 4);
                dsum[t][0] += v.x; dsum[t][1] += v.y; dsum[t][2] += v.z; dsum[t][3] += v.w;
            }
            #pragma unroll
            for (int r = 0; r < 4; ++r) x2r[r] += x2part[wv][quad * 4 + r];
            #pragma unroll
            for (int t = 0; t < 4; ++t) p2c[t] += p2part[wv][t * 16 + l15];
        }
        float vc[4];
        #pragma unroll
        for (int t = 0; t < 4; ++t) vc[t] = V[t * 16 + l15];

        float lossAcc = 0.0f;
        #pragma unroll
        for (int r = 0; r < 4; ++r) {
            float lg[4];
            #pragma unroll
            for (int t = 0; t < 4; ++t)
                lg[t] = (2.0f * dsum[t][r] - x2r[r] - p2c[t]) / vc[t];
            float mx = fmaxf(fmaxf(lg[0], lg[1]), fmaxf(lg[2], lg[3]));
            #pragma unroll
            for (int dl = 1; dl <= 8; dl <<= 1) mx = fmaxf(mx, __shfl_xor(mx, dl));
            float s = expf(lg[0] - mx) + expf(lg[1] - mx)
                    + expf(lg[2] - mx) + expf(lg[3] - mx);
            #pragma unroll
            for (int dl = 1; dl <= 8; dl <<= 1) s += __shfl_xor(s, dl);
            const float lse = mx + logf(s);
            const int row = quad * 4 + r;
            #pragma unroll
            for (int t = 0; t < 4; ++t) {
                const int col = t * 16 + l15;
                if (col == y) lossAcc += w * (lse - lg[t]);
                atomicAdd(&predL[row * PSTRIDE + col], w * expf(lg[t] - lse));
            }
        }
        #pragma unroll
        for (int dl = 1; dl <= 32; dl <<= 1) lossAcc += __shfl_xor(lossAcc, dl);
        if (lane == 0) atomicAdd(&lossL, lossAcc);
    }
    __syncthreads();

    if (wave == 0) {
        float cnt = 0.0f;
        #pragma unroll 1
        for (int r = 0; r < 16; ++r) {
            float bv = predL[r * PSTRIDE + lane];
            int   bc = lane;
            #pragma unroll
            for (int dl = 1; dl <= 32; dl <<= 1) {
                const float ov = __shfl_xor(bv, dl);
                const int   oc = __shfl_xor(bc, dl);
                if (ov > bv || (ov == bv && oc < bc)) { bv = ov; bc = oc; }
            }
            if (lane == 0 && bc == y) cnt += 1.0f;
        }
        if (lane == 0) {
            atomicAdd(&out[0], lossL * (1.0f / NROWS));
            atomicAdd(&out[1], cnt * (1.0f / NROWS));
        }
    }
}

extern "C" void kernel_launch(void* const* d_in, const int* in_sizes, int n_in,
                              void* d_out, int out_size, void* d_ws, size_t ws_size,
                              hipStream_t stream) {
    const float* Xtf = (const float*)d_in[0];
    const float* Ptf = (const float*)d_in[1];
    const float* Vtf = (const float*)d_in[2];
    const float* Xde = (const float*)d_in[3];
    const float* Pde = (const float*)d_in[4];
    const float* Vde = (const float*)d_in[5];
    const float* Xff = (const float*)d_in[6];
    const float* Pff = (const float*)d_in[7];
    const float* Vff = (const float*)d_in[8];
    float* out = (float*)d_out;

    hipMemsetAsync(out, 0, 2 * sizeof(float), stream);

    if (ws_size >= (size_t)WS_NEED) {
        _Float16* W  = (_Float16*)d_ws;
        float*    p2 = (float*)((char*)d_ws + WPROTO_BYTES);
        hipMemsetAsync(p2, 0, 3 * NCLS * sizeof(float), stream);
        prep_protos<<<dim3(96), dim3(64), 0, stream>>>(Ptf, Pde, Pff, W, p2);
        fusion_loss_kernel<<<dim3(NROWS / 16), dim3(NWAVES * 64), 0, stream>>>(
            Xtf, Vtf, Xde, Vde, Xff, Vff, W, p2, out);
    } else {
        fusion_loss_fallback<<<dim3(NROWS / 16), dim3(NWAVES * 64), 0, stream>>>(
            Xtf, Ptf, Vtf, Xde, Pde, Vde, Xff, Pff, Vff, out);
    }
}